// Round 7
// baseline (522.900 us; speedup 1.0000x reference)
//
#include <hip/hip_runtime.h>
#include <math.h>

// ConvGRU v15: = v14 (persistent wavefront + f16 partial-sum shipping,
// workspace-safe 4.08MB) with the COMPILE FIX: inline-asm operands must be
// ext_vector_type, not HIP's struct uint4 ("indirect register inputs" error).
// v12/v13 post-mortem: run-dependent error ~1.9 = poison readback; suspect
// d_ws overflow (they assumed 16.1MB; passing kernels used <= 4.27MB).
// v14/v15 layout: [0,4MB) f16 partial slots, [4MB,+72KB) wfrag, +74KB flags.
//  - partials shipped as PACKED F16 (pack2): sums of f16xf16 products; one
//    extra f16 rounding of an O(1) value adds ~1e-3 pre-activation error,
//    far under the 0.02 threshold.
//  - single-buffer slots + ACK flags: producer (y,dir) spins kflag >= t
//    before shipping slot t; consumer acks slot(t) at top of step t+1 (after
//    its final barrier -> all its reads of slot t complete). Deadlock-free
//    by induction; ack(t) posted before the consumer's own S-poll.
// Structure = v12: out(y,t) = C_x + C_h(ky1 own) + C_h(ky0 from y-1) +
// C_h(ky2 from y+1); kh0 wave: 12 x-chunks->accS + 8 ky0->accX (ship up);
// kh1 wave: 8 ky1->accS + 8 ky2->accX (ship down). All GEMM inputs local;
// consumer adds received f16 tiles (same C-fragment layout). Publish chain
// per v10/v11: explicit vmcnt(0) drain -> barrier -> relaxed agent add.

typedef _Float16 half8 __attribute__((ext_vector_type(8)));
typedef float floatx16 __attribute__((ext_vector_type(16)));
typedef unsigned uintx4 __attribute__((ext_vector_type(4)));

#define NROW 80                      // staged k-rows: 48 x + 32 own-h
#define RS 144                       // bytes per staged k-row (both copies)
#define CP1 (NROW * RS)              // copy1 byte base (11520)
#define SCRDW (2 * NROW * 36)        // scratch dword base (5760)
#define LDS_DW (SCRDW + 4 * 16 * 68) // + 4 tiles x 16 regs x 68-stride (10112 dw)

static __device__ __forceinline__ unsigned pack2(float a, float b) {
    _Float16 ha = (_Float16)a, hb = (_Float16)b;
    unsigned short ua = *(unsigned short*)&ha, ub = *(unsigned short*)&hb;
    return (unsigned)ua | ((unsigned)ub << 16);
}
static __device__ __forceinline__ float f16lo(unsigned d) {
    unsigned short u = (unsigned short)(d & 0xffffu);
    _Float16 h = *(_Float16*)&u; return (float)h;
}
static __device__ __forceinline__ float f16hi(unsigned d) {
    unsigned short u = (unsigned short)(d >> 16);
    _Float16 h = *(_Float16*)&u; return (float)h;
}

// device-coherent (sc0 sc1) ops: L1/L2 bypass, served at device coherence pt
static __device__ __forceinline__ void st_dc4u(unsigned* p, uintx4 v) {
    asm volatile("global_store_dwordx4 %0, %1, off sc0 sc1"
                 :: "v"(p), "v"(v) : "memory");
}
static __device__ __forceinline__ void drain_vm() {
    asm volatile("s_waitcnt vmcnt(0)" ::: "memory");
}
static __device__ __forceinline__ void ld2_u4(const unsigned* p,
                                              uintx4& a0, uintx4& a1) {
    asm volatile("global_load_dwordx4 %0, %2, off sc0 sc1\n\t"
                 "global_load_dwordx4 %1, %2, off offset:16 sc0 sc1\n\t"
                 "s_waitcnt vmcnt(0)"
                 : "=&v"(a0), "=&v"(a1) : "v"(p));
}
static __device__ __forceinline__ void ld4_u4(const unsigned* p0, const unsigned* p1,
    uintx4& a0, uintx4& a1, uintx4& b0, uintx4& b1) {
    asm volatile("global_load_dwordx4 %0, %4, off sc0 sc1\n\t"
                 "global_load_dwordx4 %1, %4, off offset:16 sc0 sc1\n\t"
                 "global_load_dwordx4 %2, %5, off sc0 sc1\n\t"
                 "global_load_dwordx4 %3, %5, off offset:16 sc0 sc1\n\t"
                 "s_waitcnt vmcnt(0)"
                 : "=&v"(a0), "=&v"(a1), "=&v"(b0), "=&v"(b1)
                 : "v"(p0), "v"(p1));
}

// ---- pre-kernel: weights -> A-fragment layout, v12 k-grouping ----
// chunk c (0..35): 0..11 = x (staged rows rl = cin*3+ky, k = rl*4 + slot);
// 12..19 = h ky=1; 20..27 = h ky=0; 28..35 = h ky=2 (h B-rows = 48+cin).
// Per-row 4 k-slots: (q,o), kx = o+2q, phantom at q&o.
__global__ __launch_bounds__(64) void build_wfrag(
    const float* __restrict__ Wx, const float* __restrict__ Wh,
    uint4* __restrict__ wfrag)
{
    const int bid   = blockIdx.x;            // 0..71
    const int mtile = bid / 36, c = bid % 36;
    const int lane  = threadIdx.x;
    const int m     = lane & 31;
    const int grow  = (m < 16) ? (mtile * 16 + m) : (64 + mtile * 16 + (m - 16));
    unsigned short h[8];
    for (int j = 0; j < 8; ++j) {
        const int kl = (lane >> 5) * 8 + j;  // 0..15 within chunk
        float w = 0.0f;
        if (c < 12) {
            const int k  = c * 16 + kl;      // 0..191
            const int rl = k >> 2, t4 = k & 3;
            const int cin = rl / 3, ky = rl - cin * 3;
            const int o = t4 & 1, q = t4 >> 1, kx = o + 2 * q;
            if (!(q && o)) w = Wx[((size_t)grow * 16 + cin) * 9 + ky * 3 + kx];
        } else {
            const int cg = (c - 12) >> 3;    // 0:ky1 1:ky0 2:ky2
            const int ky = (cg == 0) ? 1 : ((cg == 1) ? 0 : 2);
            const int k  = ((c - 12) & 7) * 16 + kl;   // 0..127
            const int cin = k >> 2, t4 = k & 3;
            const int o = t4 & 1, q = t4 >> 1, kx = o + 2 * q;
            if (!(q && o)) w = Wh[((size_t)grow * 32 + cin) * 9 + ky * 3 + kx];
        }
        _Float16 hw = (_Float16)w;
        h[j] = *(unsigned short*)&hw;
    }
    uint4 o4;
    o4.x = (unsigned)h[0] | ((unsigned)h[1] << 16);
    o4.y = (unsigned)h[2] | ((unsigned)h[3] << 16);
    o4.z = (unsigned)h[4] | ((unsigned)h[5] << 16);
    o4.w = (unsigned)h[6] | ((unsigned)h[7] << 16);
    wfrag[(size_t)bid * 64 + lane] = o4;
}

__global__ __launch_bounds__(512, 2) void convgru_persist(
    const float* __restrict__ x, const float* __restrict__ bx,
    const uint4* __restrict__ wfrag,
    unsigned* __restrict__ part, // f16 slots [dir][b][y][tile][lane][8dw] (4MB)
    float* __restrict__ out,     // final NCHW (t=63 only)
    int* __restrict__ sflag,     // ship flags inbox[b][y][2]
    int* __restrict__ kflag)     // ack flags  [b][y][2] (dir of producer)
{
    __shared__ unsigned plds[LDS_DW];        // staging + scratch (40,448 B)
    __shared__ uint4    wlds[72 * 64];       // A-fragments      (73,728 B)
    __shared__ float    hrow[32 * 64];       // own-row h(t-1)   ( 8,192 B)

    const int tx = threadIdx.x;
    const int y  = blockIdx.x;               // image row 0..63
    const int b  = blockIdx.y;               // batch 0..3
    const int lane  = tx & 63;
    const int wv    = tx >> 6;               // 0..7
    const int kh    = wv & 1;                // role: 0 = x+ky0, 1 = ky1+ky2
    const int mtile = (wv >> 1) & 1;
    const int ntile = wv >> 2;
    const int tile  = wv >> 1;               // 0..3 (shared by kh pair)
    const int xpx   = ntile * 32 + (lane & 31);
    const int half  = lane >> 5;
    const int lb_off = ((xpx & 1) ? (2 * xpx + 6) : (CP1 + 2 * xpx))
                       + half * (2 * RS);
    const char* lbase = (const char*)plds + lb_off;

    // one-time setup
    #pragma unroll
    for (int i = 0; i < 9; ++i) wlds[i * 512 + tx] = wfrag[i * 512 + tx];
    if (tx < NROW) plds[tx * 36 + 34] = 0u;          // copy0 right-halo dword
    ((float4*)hrow)[tx] = make_float4(0.f, 0.f, 0.f, 0.f);   // h0 = 0
    __syncthreads();

    int* const inbox = sflag + (b * 64 + y) * 2;

    float hcur[8];
    #pragma unroll
    for (int r = 0; r < 8; ++r) hcur[r] = 0.0f;
    float bz[8], bn[8];
    #pragma unroll
    for (int r = 0; r < 8; ++r) {
        const int row = (r & 3) + 8 * (r >> 2) + 4 * half;
        const int oc  = mtile * 16 + row;
        bz[r] = bx[oc]; bn[r] = bx[64 + oc];
    }

    #pragma unroll 1
    for (int t = 0; t < 64; ++t) {
        // ---- (0) ack step t-1's slot reads (frees producers to ship t) ----
        // After iter t-1's final barrier, so ALL kh0 waves' reads are done.
        if (t > 0 && wv == 0 && lane < 2) {
            const int yy = lane ? (y + 1) : (y - 1);   // lane0: prod y-1 dir0
            if (0 <= yy && yy < 64)                    // lane1: prod y+1 dir1
                __hip_atomic_fetch_add(kflag + (b * 64 + yy) * 2 + lane, 1,
                                       __ATOMIC_RELAXED, __HIP_MEMORY_SCOPE_AGENT);
        }

        // ---- x prefetch (rows 0..47 = cin*3+ky, all local) ----
        float4 xv0 = make_float4(0.f, 0.f, 0.f, 0.f), xv1 = xv0;
        {
            const int rr = tx >> 4, g = tx & 15;       // tasks 0..511
            const int cin = rr / 3, ky = rr - cin * 3, ys = y + ky - 1;
            if ((unsigned)ys < 64u)
                xv0 = *(const float4*)(x + (((size_t)(b * 16 + cin) * 64 + t) * 4096)
                                         + ys * 64 + g * 4);
        }
        if (tx < 256) {
            const int task = 512 + tx;                 // tasks 512..767
            const int rr = task >> 4, g = task & 15;
            const int cin = rr / 3, ky = rr - cin * 3, ys = y + ky - 1;
            if ((unsigned)ys < 64u)
                xv1 = *(const float4*)(x + (((size_t)(b * 16 + cin) * 64 + t) * 4096)
                                         + ys * 64 + g * 4);
        }

        // ---- x -> LDS (parity copies) ----
        {
            const int rr = tx >> 4, g = tx & 15;
            float prev = __shfl_up(xv0.w, 1);
            if (g == 0) prev = 0.f;
            const int r36 = rr * 36;
            plds[r36 + 2 * g + 2] = pack2(xv0.x, xv0.y);
            plds[r36 + 2 * g + 3] = pack2(xv0.z, xv0.w);
            plds[CP1 / 4 + r36 + 2 * g]     = pack2(prev, xv0.x);
            plds[CP1 / 4 + r36 + 2 * g + 1] = pack2(xv0.y, xv0.z);
            if (g == 15) plds[CP1 / 4 + r36 + 32] = pack2(xv0.w, 0.f);
        }
        if (tx < 256) {
            const int task = 512 + tx;
            const int rr = task >> 4, g = task & 15;
            float prev = __shfl_up(xv1.w, 1);
            if (g == 0) prev = 0.f;
            const int r36 = rr * 36;
            plds[r36 + 2 * g + 2] = pack2(xv1.x, xv1.y);
            plds[r36 + 2 * g + 3] = pack2(xv1.z, xv1.w);
            plds[CP1 / 4 + r36 + 2 * g]     = pack2(prev, xv1.x);
            plds[CP1 / 4 + r36 + 2 * g + 1] = pack2(xv1.y, xv1.z);
            if (g == 15) plds[CP1 / 4 + r36 + 32] = pack2(xv1.w, 0.f);
        }

        // ---- own-h(t-1) -> LDS rows 48..79 (from hrow; 512 tasks) ----
        {
            const int cin = tx >> 4, g = tx & 15;      // cin 0..31
            const int rr  = 48 + cin;
            float4 v = *(const float4*)(hrow + cin * 64 + g * 4);
            float prev = __shfl_up(v.w, 1);
            if (g == 0) prev = 0.f;
            const int r36 = rr * 36;
            plds[r36 + 2 * g + 2] = pack2(v.x, v.y);
            plds[r36 + 2 * g + 3] = pack2(v.z, v.w);
            plds[CP1 / 4 + r36 + 2 * g]     = pack2(prev, v.x);
            plds[CP1 / 4 + r36 + 2 * g + 1] = pack2(v.y, v.z);
            if (g == 15) plds[CP1 / 4 + r36 + 32] = pack2(v.w, 0.f);
        }
        __syncthreads();                               // stage-sync

        // ---- MFMA: all-local chunks ----
        floatx16 accS, accX;                           // X = up (kh0) / down (kh1)
        #pragma unroll
        for (int i = 0; i < 16; ++i) { accS[i] = 0.0f; accX[i] = 0.0f; }
        if (kh == 0) {
            #pragma unroll
            for (int j = 0; j < 20; ++j) {
                const int c  = (j < 12) ? j : (20 + (j - 12));
                const int rb = (j < 12) ? (4 * j) : (48 + 4 * (j - 12));
                uint4 aw = wlds[(mtile * 36 + c) * 64 + lane];
                const int B0 = rb * RS;
                unsigned d0 = *(const unsigned*)(lbase + B0);
                unsigned d1 = *(const unsigned*)(lbase + B0 + 4);
                unsigned e0 = *(const unsigned*)(lbase + B0 + RS);
                unsigned e1 = *(const unsigned*)(lbase + B0 + RS + 4);
                uint4 bf; bf.x = d0; bf.y = d1; bf.z = e0; bf.w = e1;
                union { uint4 u; half8 h; } ua, ub;
                ua.u = aw; ub.u = bf;
                if (j < 12)
                    accS = __builtin_amdgcn_mfma_f32_32x32x16_f16(ua.h, ub.h, accS, 0, 0, 0);
                else
                    accX = __builtin_amdgcn_mfma_f32_32x32x16_f16(ua.h, ub.h, accX, 0, 0, 0);
            }
        } else {
            #pragma unroll
            for (int j = 0; j < 16; ++j) {
                const int c  = (j < 8) ? (12 + j) : (28 + (j - 8));
                const int rb = 48 + 4 * ((j < 8) ? j : (j - 8));
                uint4 aw = wlds[(mtile * 36 + c) * 64 + lane];
                const int B0 = rb * RS;
                unsigned d0 = *(const unsigned*)(lbase + B0);
                unsigned d1 = *(const unsigned*)(lbase + B0 + 4);
                unsigned e0 = *(const unsigned*)(lbase + B0 + RS);
                unsigned e1 = *(const unsigned*)(lbase + B0 + RS + 4);
                uint4 bf; bf.x = d0; bf.y = d1; bf.z = e0; bf.w = e1;
                union { uint4 u; half8 h; } ua, ub;
                ua.u = aw; ub.u = bf;
                if (j < 8)
                    accS = __builtin_amdgcn_mfma_f32_32x32x16_f16(ua.h, ub.h, accS, 0, 0, 0);
                else
                    accX = __builtin_amdgcn_mfma_f32_32x32x16_f16(ua.h, ub.h, accX, 0, 0, 0);
            }
        }

        // ---- ship f16 partial tiles; ack-gated; per-wave drain ----
        if (kh == 0) {
            if (y < 63) {
                if (lane == 0) {                       // slot free when K >= t
                    while (__hip_atomic_load(kflag + (b * 64 + y) * 2 + 0,
                                             __ATOMIC_RELAXED,
                                             __HIP_MEMORY_SCOPE_AGENT) < t) { }
                }
                __builtin_amdgcn_sched_barrier(0);     // pin stores after spin
                unsigned* sp = part + ((((size_t)0 * 4 + b) * 64 + (y + 1)) * 2048)
                                    + tile * 512 + lane * 8;
                union { uintx4 q[2]; unsigned d[8]; } S;
                #pragma unroll
                for (int i = 0; i < 8; ++i) S.d[i] = pack2(accX[2*i], accX[2*i+1]);
                st_dc4u(sp, S.q[0]); st_dc4u(sp + 4, S.q[1]);
                drain_vm();
            }
        } else {
            if (y > 0) {
                if (lane == 0) {
                    while (__hip_atomic_load(kflag + (b * 64 + y) * 2 + 1,
                                             __ATOMIC_RELAXED,
                                             __HIP_MEMORY_SCOPE_AGENT) < t) { }
                }
                __builtin_amdgcn_sched_barrier(0);
                unsigned* sp = part + ((((size_t)1 * 4 + b) * 64 + (y - 1)) * 2048)
                                    + tile * 512 + lane * 8;
                union { uintx4 q[2]; unsigned d[8]; } S;
                #pragma unroll
                for (int i = 0; i < 8; ++i) S.d[i] = pack2(accX[2*i], accX[2*i+1]);
                st_dc4u(sp, S.q[0]); st_dc4u(sp + 4, S.q[1]);
                drain_vm();
            }
            // K-split self reduction: park accS in LDS scratch
            #pragma unroll
            for (int r = 0; r < 16; ++r)
                plds[SCRDW + tile * 1088 + r * 68 + lane] = __float_as_uint(accS[r]);
        }
        __syncthreads();                               // all ships drained

        // ---- S-flags out, then poll own inbox ----
        if (wv == 0 && lane == 0) {
            if (y < 63)
                __hip_atomic_fetch_add(sflag + (b * 64 + y + 1) * 2 + 0, 1,
                                       __ATOMIC_RELAXED, __HIP_MEMORY_SCOPE_AGENT);
            if (y > 0)
                __hip_atomic_fetch_add(sflag + (b * 64 + y - 1) * 2 + 1, 1,
                                       __ATOMIC_RELAXED, __HIP_MEMORY_SCOPE_AGENT);
        }
        if (wv == 0 && lane < 2) {
            const bool valid = lane ? (y < 63) : (y > 0);
            if (valid) {
                while (__hip_atomic_load(inbox + lane, __ATOMIC_RELAXED,
                                         __HIP_MEMORY_SCOPE_AGENT) < t + 1) { }
            }
        }
        __syncthreads();                               // partials visible

        if (kh == 0) {
            #pragma unroll
            for (int r = 0; r < 16; ++r)
                accS[r] += __uint_as_float(plds[SCRDW + tile * 1088 + r * 68 + lane]);

            // receive neighbor f16 partials (one batched coherent-load leg)
            uintx4 a0, a1, b0, b1;
            a0 = (uintx4)(0u); a1 = (uintx4)(0u);
            b0 = (uintx4)(0u); b1 = (uintx4)(0u);
            const unsigned* p0 = part + ((((size_t)0 * 4 + b) * 64 + y) * 2048)
                                      + tile * 512 + lane * 8;
            const unsigned* p1 = part + ((((size_t)1 * 4 + b) * 64 + y) * 2048)
                                      + tile * 512 + lane * 8;
            if (y > 0 && y < 63)      ld4_u4(p0, p1, a0, a1, b0, b1);
            else if (y > 0)           ld2_u4(p0, a0, a1);
            else                      ld2_u4(p1, b0, b1);
            union { uintx4 q[2]; unsigned d[8]; } A, B;
            A.q[0] = a0; A.q[1] = a1; B.q[0] = b0; B.q[1] = b1;
            #pragma unroll
            for (int i = 0; i < 8; ++i) {
                accS[2*i]   += f16lo(A.d[i]) + f16lo(B.d[i]);
                accS[2*i+1] += f16hi(A.d[i]) + f16hi(B.d[i]);
            }

            // epilogue: gates + h update
            #pragma unroll
            for (int r = 0; r < 8; ++r) {
                const int row = (r & 3) + 8 * (r >> 2) + 4 * half;
                const int oc  = mtile * 16 + row;
                float zp = accS[r]     + bz[r];
                float np = accS[r + 8] + bn[r];
                float z  = 1.0f / (1.0f + __expf(-zp));
                float e  = __expf(2.0f * np);
                float n  = 1.0f - 2.0f / (e + 1.0f);               // tanh
                float hn = (1.0f - z) * hcur[r] + z * n;
                hcur[r] = hn;
                if (t == 63)
                    out[(size_t)(b * 32 + oc) * 4096 + y * 64 + xpx] = hn;
                else
                    hrow[oc * 64 + xpx] = hn;
            }
        }
        __syncthreads();                               // hrow + reads complete
    }
}

extern "C" void kernel_launch(void* const* d_in, const int* in_sizes, int n_in,
                              void* d_out, int out_size, void* d_ws, size_t ws_size,
                              hipStream_t stream) {
    const float* x  = (const float*)d_in[0];
    const float* Wx = (const float*)d_in[1];
    const float* bx = (const float*)d_in[2];
    const float* Wh = (const float*)d_in[3];
    float*    out   = (float*)d_out;
    unsigned* part  = (unsigned*)d_ws;                       // 4 MB f16 slots
    uint4*    wfrag = (uint4*)((char*)d_ws + (4u << 20));    // 72 KB A-frags
    int*      sflag = (int*)((char*)d_ws + (4u << 20) + (74u << 10)); // 2 KB
    int*      kflag = sflag + 512;                                    // 2 KB

    (void)hipMemsetAsync(sflag, 0, 4096, stream);            // S + K flags
    hipLaunchKernelGGL(build_wfrag, dim3(72), dim3(64), 0, stream, Wx, Wh, wfrag);

    void* args[] = { (void*)&x, (void*)&bx, (void*)&wfrag,
                     (void*)&part, (void*)&out, (void*)&sflag, (void*)&kflag };
    (void)hipLaunchCooperativeKernel((const void*)convgru_persist,
                                     dim3(64, 4), dim3(512), args, 0, stream);
}